// Round 3
// baseline (18380.501 us; speedup 1.0000x reference)
//
#include <hip/hip_runtime.h>
#include <hip/hip_bf16.h>
#include <cstddef>

typedef __hip_bfloat16 bf16;

static __device__ __forceinline__ float b2f(bf16 v) { return __bfloat162float(v); }
static __device__ __forceinline__ float ldf(const bf16* p) { return __bfloat162float(*p); }
static __device__ __forceinline__ float ldf(const float* p) { return *p; }

// --------------------------------------------------------- dtype detection
// x is uniform[0,1). If the buffer is bf16, all 256 leading bf16 values lie
// in [0,1]. If it is fp32 misread as bf16, even-index elements are the low
// mantissa bits (random sign/exponent) -> all-pass prob ~0. flag=1 => bf16.
__global__ void detect_dtype_kernel(const void* __restrict__ x, int* __restrict__ flag) {
  __shared__ int ok;
  if (threadIdx.x == 0) ok = 1;
  __syncthreads();
  float v = b2f(((const bf16*)x)[threadIdx.x]);
  if (!(v >= 0.f && v <= 1.0009765625f)) ok = 0;   // NaN fails too
  __syncthreads();
  if (threadIdx.x == 0) *flag = ok;
}

// Convert one input tensor to fp32 based on the device flag.
__global__ void convert_kernel(const void* __restrict__ src, float* __restrict__ dst,
                               int n, const int* __restrict__ flag) {
  int i = blockIdx.x * blockDim.x + threadIdx.x;
  if (i >= n) return;
  dst[i] = (*flag) ? b2f(((const bf16*)src)[i]) : ((const float*)src)[i];
}

// ---------------------------------------------------------------- utilities
__global__ void zero2_kernel(float* p) {
  if (threadIdx.x < 2) p[threadIdx.x] = 0.f;
}

__global__ void embsq_kernel(const float* __restrict__ emb, float* __restrict__ out) {
  int k = blockIdx.x * blockDim.x + threadIdx.x;
  if (k >= 512) return;
  float s = 0.f;
  for (int c = 0; c < 128; ++c) { float e = emb[k * 128 + c]; s = fmaf(e, e, s); }
  out[k] = s;
}

// ------------------------------------------------- conv k=4 s=2 p=1 + ReLU
template <typename TIN>
static __device__ __forceinline__ void conv1_body(const TIN* __restrict__ in,
                                                  const float* __restrict__ w,
                                                  const float* __restrict__ bias,
                                                  float* __restrict__ out, long long i) {
  const int H = 256, W = 256, Cin = 3, Cout = 64;
  const int Ho = 128, Wo = 128;
  int wo = (int)(i % Wo); long long t = i / Wo;
  int ho = (int)(t % Ho); t /= Ho;
  int co = (int)(t % Cout); int b = (int)(t / Cout);
  float acc = bias[co];
  const int ih0 = ho * 2 - 1, iw0 = wo * 2 - 1;
  for (int ci = 0; ci < Cin; ++ci) {
    const TIN* ip = in + (size_t)(b * Cin + ci) * H * W;
    const float* wp = w + (size_t)(co * Cin + ci) * 16;
    #pragma unroll
    for (int kh = 0; kh < 4; ++kh) {
      int ih = ih0 + kh;
      if ((unsigned)ih >= (unsigned)H) continue;
      const TIN* row = ip + (size_t)ih * W;
      #pragma unroll
      for (int kw = 0; kw < 4; ++kw) {
        int iw = iw0 + kw;
        if ((unsigned)iw < (unsigned)W)
          acc = fmaf(ldf(&row[iw]), wp[kh * 4 + kw], acc);
      }
    }
  }
  out[i] = fmaxf(acc, 0.f);
}

__global__ void conv1_kernel(const void* __restrict__ x, const int* __restrict__ flag,
                             const float* __restrict__ w, const float* __restrict__ bias,
                             float* __restrict__ out) {
  const long long total = 16LL * 64 * 128 * 128;
  long long i = (long long)blockIdx.x * blockDim.x + threadIdx.x;
  if (i >= total) return;
  if (*flag) conv1_body<bf16>((const bf16*)x, w, bias, out, i);
  else       conv1_body<float>((const float*)x, w, bias, out, i);
}

// generic fp32-in conv k=4 s=2 p=1 + ReLU
__global__ void conv_relu_kernel(const float* __restrict__ in, const float* __restrict__ w,
                                 const float* __restrict__ bias, float* __restrict__ out,
                                 int B, int Cin, int Cout, int H, int W) {
  const int Ho = H >> 1, Wo = W >> 1;
  const long long total = (long long)B * Cout * Ho * Wo;
  long long i = (long long)blockIdx.x * blockDim.x + threadIdx.x;
  if (i >= total) return;
  int wo = (int)(i % Wo); long long t = i / Wo;
  int ho = (int)(t % Ho); t /= Ho;
  int co = (int)(t % Cout); int b = (int)(t / Cout);
  float acc = bias[co];
  const int ih0 = ho * 2 - 1, iw0 = wo * 2 - 1;
  for (int ci = 0; ci < Cin; ++ci) {
    const float* ip = in + (size_t)(b * Cin + ci) * H * W;
    const float* wp = w + (size_t)(co * Cin + ci) * 16;
    #pragma unroll
    for (int kh = 0; kh < 4; ++kh) {
      int ih = ih0 + kh;
      if ((unsigned)ih >= (unsigned)H) continue;
      const float* row = ip + (size_t)ih * W;
      #pragma unroll
      for (int kw = 0; kw < 4; ++kw) {
        int iw = iw0 + kw;
        if ((unsigned)iw < (unsigned)W)
          acc = fmaf(row[iw], wp[kh * 4 + kw], acc);
      }
    }
  }
  out[i] = fmaxf(acc, 0.f);
}

// ------------------------------------------------------------- VQ quantize
__global__ __launch_bounds__(256) void vq_kernel(const float* __restrict__ z,
                                                 const float* __restrict__ emb,
                                                 const float* __restrict__ embsq,
                                                 float* __restrict__ zq,
                                                 float* __restrict__ loss_acc, int HW) {
  __shared__ float se[64 * 128];
  __shared__ float ssq[64];
  const int n = blockIdx.x * 256 + threadIdx.x;   // grid sized so N % 256 == 0
  const int b = n / HW, hw = n % HW;
  const float* zbase = z + (size_t)b * 128 * HW + hw;
  float zp[128];
  #pragma unroll
  for (int c = 0; c < 128; ++c) zp[c] = zbase[(size_t)c * HW];

  float best = 3.4e38f; int bestk = 0;
  for (int k0 = 0; k0 < 512; k0 += 64) {
    __syncthreads();
    #pragma unroll
    for (int tt = 0; tt < 32; ++tt) {
      int idx = tt * 256 + threadIdx.x;
      se[idx] = emb[(size_t)k0 * 128 + idx];
    }
    if (threadIdx.x < 64) ssq[threadIdx.x] = embsq[k0 + threadIdx.x];
    __syncthreads();
    for (int kk = 0; kk < 64; kk += 4) {
      float d0 = 0.f, d1 = 0.f, d2 = 0.f, d3 = 0.f;
      const float* e0 = se + kk * 128;
      #pragma unroll
      for (int c = 0; c < 128; ++c) {
        float zc = zp[c];
        d0 = fmaf(zc, e0[c], d0);
        d1 = fmaf(zc, e0[128 + c], d1);
        d2 = fmaf(zc, e0[256 + c], d2);
        d3 = fmaf(zc, e0[384 + c], d3);
      }
      float s0 = fmaf(-2.f, d0, ssq[kk + 0]);
      float s1 = fmaf(-2.f, d1, ssq[kk + 1]);
      float s2 = fmaf(-2.f, d2, ssq[kk + 2]);
      float s3 = fmaf(-2.f, d3, ssq[kk + 3]);
      if (s0 < best) { best = s0; bestk = k0 + kk + 0; }
      if (s1 < best) { best = s1; bestk = k0 + kk + 1; }
      if (s2 < best) { best = s2; bestk = k0 + kk + 2; }
      if (s3 < best) { best = s3; bestk = k0 + kk + 3; }
    }
  }

  float lsum = 0.f;
  const float* eb = emb + (size_t)bestk * 128;
  float* zqb = zq + (size_t)b * 128 * HW + hw;
  #pragma unroll
  for (int c = 0; c < 128; ++c) {
    float ev = eb[c];
    zqb[(size_t)c * HW] = ev;
    float dv = ev - zp[c];
    lsum = fmaf(dv, dv, lsum);
  }
  for (int o = 32; o > 0; o >>= 1) lsum += __shfl_down(lsum, o, 64);
  if ((threadIdx.x & 63) == 0) atomicAdd(loss_acc, lsum);
}

// -------------------------------------------- convT k=4 s=2 p=1 (+ReLU)
__global__ void convT_relu_kernel(const float* __restrict__ in0, const float* __restrict__ in1,
                                  int Cin0, int Cin, const float* __restrict__ w,
                                  const float* __restrict__ bias, float* __restrict__ out,
                                  int B, int Cout, int H, int W) {
  const int Ho = H * 2, Wo = W * 2;
  const long long total = (long long)B * Cout * Ho * Wo;
  long long i = (long long)blockIdx.x * blockDim.x + threadIdx.x;
  if (i >= total) return;
  int ow = (int)(i % Wo); long long t = i / Wo;
  int oh = (int)(t % Ho); t /= Ho;
  int co = (int)(t % Cout); int b = (int)(t / Cout);
  int khs[2], ihs[2], nh = 0;
  #pragma unroll
  for (int kh = (oh + 1) & 1; kh < 4; kh += 2) {
    int ih = (oh + 1 - kh) >> 1;
    if ((unsigned)ih < (unsigned)H) { khs[nh] = kh; ihs[nh] = ih; ++nh; }
  }
  int kws[2], iws[2], nw = 0;
  #pragma unroll
  for (int kw = (ow + 1) & 1; kw < 4; kw += 2) {
    int iw = (ow + 1 - kw) >> 1;
    if ((unsigned)iw < (unsigned)W) { kws[nw] = kw; iws[nw] = iw; ++nw; }
  }
  float acc = bias[co];
  const int HW = H * W;
  for (int ci = 0; ci < Cin; ++ci) {
    const float* ip = (ci < Cin0) ? (in0 + (size_t)(b * Cin0 + ci) * HW)
                                  : (in1 + (size_t)(b * (Cin - Cin0) + (ci - Cin0)) * HW);
    const float* wp = w + (size_t)(ci * Cout + co) * 16;
    for (int a = 0; a < nh; ++a) {
      const float* row = ip + (size_t)ihs[a] * W;
      for (int c2 = 0; c2 < nw; ++c2)
        acc = fmaf(row[iws[c2]], wp[khs[a] * 4 + kws[c2]], acc);
    }
  }
  out[i] = fmaxf(acc, 0.f);
}

// final convT + sigmoid -> fp32 output
__global__ void convT_sigmoid_kernel(const float* __restrict__ in, const float* __restrict__ w,
                                     const float* __restrict__ bias, float* __restrict__ out,
                                     int B, int Cin, int Cout, int H, int W) {
  const int Ho = H * 2, Wo = W * 2;
  const long long total = (long long)B * Cout * Ho * Wo;
  long long i = (long long)blockIdx.x * blockDim.x + threadIdx.x;
  if (i >= total) return;
  int ow = (int)(i % Wo); long long t = i / Wo;
  int oh = (int)(t % Ho); t /= Ho;
  int co = (int)(t % Cout); int b = (int)(t / Cout);
  int khs[2], ihs[2], nh = 0;
  #pragma unroll
  for (int kh = (oh + 1) & 1; kh < 4; kh += 2) {
    int ih = (oh + 1 - kh) >> 1;
    if ((unsigned)ih < (unsigned)H) { khs[nh] = kh; ihs[nh] = ih; ++nh; }
  }
  int kws[2], iws[2], nw = 0;
  #pragma unroll
  for (int kw = (ow + 1) & 1; kw < 4; kw += 2) {
    int iw = (ow + 1 - kw) >> 1;
    if ((unsigned)iw < (unsigned)W) { kws[nw] = kw; iws[nw] = iw; ++nw; }
  }
  float acc = bias[co];
  const int HW = H * W;
  for (int ci = 0; ci < Cin; ++ci) {
    const float* ip = in + (size_t)(b * Cin + ci) * HW;
    const float* wp = w + (size_t)(ci * Cout + co) * 16;
    for (int a = 0; a < nh; ++a) {
      const float* row = ip + (size_t)ihs[a] * W;
      for (int c2 = 0; c2 < nw; ++c2)
        acc = fmaf(row[iws[c2]], wp[khs[a] * 4 + kws[c2]], acc);
    }
  }
  out[i] = 1.f / (1.f + expf(-acc));
}

__global__ void finalize_loss_kernel(const float* __restrict__ lacc, float* __restrict__ out) {
  if (threadIdx.x == 0) {
    float lt = lacc[0] * (1.5f / (16384.f * 128.f));
    float lb = lacc[1] * (1.5f / (65536.f * 128.f));
    *out = lt + lb;
  }
}

// ------------------------------------------------------------------ launch
extern "C" void kernel_launch(void* const* d_in, const int* in_sizes, int n_in,
                              void* d_out, int out_size, void* d_ws, size_t ws_size,
                              hipStream_t stream) {
  const void* x = d_in[0];
  float* out = (float*)d_out;   // fp32 output per reference dtypes

  // workspace layout
  int* flag = (int*)d_ws;
  float* ws = (float*)d_ws + 16;   // 64B after flag
  size_t off = 0;
  auto alloc = [&](size_t n) { float* p = ws + off; off += (n + 15) & ~(size_t)15; return p; };

  // fp32 copies of all non-x inputs (indices 1..14)
  const int nconv = 14;
  const int conv_n[nconv] = {3072, 64, 131072, 128, 262144, 128, 65536, 65536,
                             262144, 128, 262144, 64, 3072, 3};
  float* cv[nconv];
  for (int j = 0; j < nconv; ++j) cv[j] = alloc((size_t)conv_n[j]);

  float* A    = alloc((size_t)16 * 64 * 128 * 128);   // act1, later h
  float* Bz   = alloc((size_t)16 * 128 * 64 * 64);    // z_bottom
  float* Ct   = alloc((size_t)16 * 128 * 32 * 32);    // z_top
  float* Dq   = alloc((size_t)16 * 128 * 32 * 32);    // z_top_q
  float* Eu   = alloc((size_t)16 * 128 * 64 * 64);    // z_top_up
  float* Fq   = alloc((size_t)16 * 128 * 64 * 64);    // z_bottom_q
  float* sq_t = alloc(512);
  float* sq_b = alloc(512);
  float* lacc = alloc(16);

  float* we_b1 = cv[0];  float* be_b1 = cv[1];
  float* we_b2 = cv[2];  float* be_b2 = cv[3];
  float* we_t  = cv[4];  float* be_t  = cv[5];
  float* emb_t = cv[6];  float* emb_b = cv[7];
  float* wd_t  = cv[8];  float* bd_t  = cv[9];
  float* wd1   = cv[10]; float* bd1   = cv[11];
  float* wd2   = cv[12]; float* bd2   = cv[13];

  const int BLK = 256;
  auto blocks = [&](long long n) { return (unsigned)((n + BLK - 1) / BLK); };

  detect_dtype_kernel<<<1, 256, 0, stream>>>(x, flag);
  for (int j = 0; j < nconv; ++j)
    convert_kernel<<<blocks(conv_n[j]), BLK, 0, stream>>>(d_in[j + 1], cv[j], conv_n[j], flag);

  zero2_kernel<<<1, 64, 0, stream>>>(lacc);
  embsq_kernel<<<2, 256, 0, stream>>>(emb_t, sq_t);
  embsq_kernel<<<2, 256, 0, stream>>>(emb_b, sq_b);

  // encoder
  conv1_kernel<<<blocks(16LL * 64 * 128 * 128), BLK, 0, stream>>>(x, flag, we_b1, be_b1, A);
  conv_relu_kernel<<<blocks(16LL * 128 * 64 * 64), BLK, 0, stream>>>(
      A, we_b2, be_b2, Bz, 16, 64, 128, 128, 128);
  conv_relu_kernel<<<blocks(16LL * 128 * 32 * 32), BLK, 0, stream>>>(
      Bz, we_t, be_t, Ct, 16, 128, 128, 64, 64);

  // VQ top (N = 16*1024 = 16384)
  vq_kernel<<<16384 / 256, 256, 0, stream>>>(Ct, emb_t, sq_t, Dq, lacc + 0, 1024);

  // decoder_top upsample
  convT_relu_kernel<<<blocks(16LL * 128 * 64 * 64), BLK, 0, stream>>>(
      Dq, nullptr, 128, 128, wd_t, bd_t, Eu, 16, 128, 32, 32);

  // VQ bottom (N = 16*4096 = 65536)
  vq_kernel<<<65536 / 256, 256, 0, stream>>>(Bz, emb_b, sq_b, Fq, lacc + 1, 4096);

  // decoder: concat(z_bottom_q, z_top_up) -> convT -> relu -> h (reuse A)
  convT_relu_kernel<<<blocks(16LL * 64 * 128 * 128), BLK, 0, stream>>>(
      Fq, Eu, 128, 256, wd1, bd1, A, 16, 64, 64, 64);

  // final convT + sigmoid, fp32 output
  convT_sigmoid_kernel<<<blocks(16LL * 3 * 256 * 256), BLK, 0, stream>>>(
      A, wd2, bd2, out, 16, 64, 3, 128, 128);

  finalize_loss_kernel<<<1, 64, 0, stream>>>(lacc, out + (size_t)16 * 3 * 256 * 256);
}

// Round 4
// 2768.966 us; speedup vs baseline: 6.6380x; 6.6380x over previous
//
#include <hip/hip_runtime.h>
#include <hip/hip_bf16.h>
#include <cstddef>

typedef __hip_bfloat16 bf16;
typedef __attribute__((ext_vector_type(8))) short short8;
typedef __attribute__((ext_vector_type(4))) float float4v;
typedef __attribute__((ext_vector_type(4))) unsigned short ushort4v;

static __device__ __forceinline__ float b2f(bf16 v) { return __bfloat162float(v); }
static __device__ __forceinline__ float bits2f(unsigned int u) { return __uint_as_float(u); }
static __device__ __forceinline__ unsigned short f2bfbits(float f) {
  bf16 h = __float2bfloat16(f);
  return *reinterpret_cast<unsigned short*>(&h);
}
static __device__ __forceinline__ float ld_any(const void* p, long i, int flag) {
  return flag ? b2f(((const bf16*)p)[i]) : ((const float*)p)[i];
}
static __device__ __forceinline__ void unpack_u4(uint4 u, float* f) {
  f[0] = bits2f(u.x << 16); f[1] = bits2f(u.x & 0xffff0000u);
  f[2] = bits2f(u.y << 16); f[3] = bits2f(u.y & 0xffff0000u);
  f[4] = bits2f(u.z << 16); f[5] = bits2f(u.z & 0xffff0000u);
  f[6] = bits2f(u.w << 16); f[7] = bits2f(u.w & 0xffff0000u);
}

// --------------------------------------------------------- dtype detection
__global__ void detect_dtype_kernel(const void* __restrict__ x, int* __restrict__ flag) {
  __shared__ int ok;
  if (threadIdx.x == 0) ok = 1;
  __syncthreads();
  float v = b2f(((const bf16*)x)[threadIdx.x]);
  if (!(v >= 0.f && v <= 1.0009765625f)) ok = 0;
  __syncthreads();
  if (threadIdx.x == 0) *flag = ok;
}

// ---------------------------------------------------------------- utilities
__global__ void zero_kernel(uint4* __restrict__ p, long n4) {
  long i = (long)blockIdx.x * blockDim.x + threadIdx.x;
  long stride = (long)gridDim.x * blockDim.x;
  uint4 z = {0u, 0u, 0u, 0u};
  for (; i < n4; i += stride) p[i] = z;
}
__global__ void zero2_kernel(float* p) {
  if (threadIdx.x < 2) p[threadIdx.x] = 0.f;
}
__global__ void conv_f32(const void* __restrict__ src, float* __restrict__ dst,
                         int n, const int* __restrict__ flag) {
  int i = blockIdx.x * blockDim.x + threadIdx.x;
  if (i < n) dst[i] = ld_any(src, i, *flag);
}
__global__ void conv_bf16(const void* __restrict__ src, bf16* __restrict__ dst,
                          int n, const int* __restrict__ flag) {
  int i = blockIdx.x * blockDim.x + threadIdx.x;
  if (i >= n) return;
  dst[i] = (*flag) ? ((const bf16*)src)[i] : __float2bfloat16(((const float*)src)[i]);
}
__global__ void embsq_kernel(const bf16* __restrict__ emb, float* __restrict__ out) {
  int k = blockIdx.x * blockDim.x + threadIdx.x;
  if (k >= 512) return;
  float s = 0.f;
  for (int c = 0; c < 128; ++c) { float e = b2f(emb[k * 128 + c]); s = fmaf(e, e, s); }
  out[k] = s;
}

// weights OIHW [CO][CI][4][4] -> [tap=kh*4+kw][co][ci] bf16
template <int CO, int CI>
__global__ void rp_conv_w(const void* __restrict__ src, bf16* __restrict__ dst,
                          const int* __restrict__ flag) {
  const int N = CO * CI * 16;
  int i = blockIdx.x * blockDim.x + threadIdx.x;
  if (i >= N) return;
  int co = i / (CI * 16);
  int rem = i % (CI * 16);
  int ci = rem >> 4;
  int k = rem & 15;
  dst[((long)k * CO + co) * CI + ci] = __float2bfloat16(ld_any(src, i, *flag));
}

// convT weights [CI][CO][4][4] -> [class pq][tap st][co][ci] bf16
// W'[p][q][s][t][co][ci] = src[ci][co][2s+1-p][2t+1-q]
template <int CI, int CO>
__global__ void rp_convt_w(const void* __restrict__ src, bf16* __restrict__ dst,
                           const int* __restrict__ flag) {
  const int N = CI * CO * 16;
  int i = blockIdx.x * blockDim.x + threadIdx.x;
  if (i >= N) return;
  int ci = i / (CO * 16);
  int rem = i % (CO * 16);
  int co = rem >> 4;
  int k = rem & 15;
  int kh = k >> 2, kw = k & 3;
  int p = (kh + 1) & 1, s = (kh - 1 + p) >> 1;
  int q = (kw + 1) & 1, t = (kw - 1 + q) >> 1;
  long d = (((long)(p * 2 + q) * 4 + (s * 2 + t)) * CO + co) * CI + ci;
  dst[d] = __float2bfloat16(ld_any(src, i, *flag));
}

// ---------------------------------------------- conv1: 3->64 s2, NCHW->NHWC(pad)
__global__ __launch_bounds__(256) void conv1_nhwc(const void* __restrict__ x,
                                                  const int* __restrict__ flag,
                                                  const float* __restrict__ wf,
                                                  const float* __restrict__ bf_,
                                                  bf16* __restrict__ act1p) {
  int tid = blockIdx.x * 256 + threadIdx.x;   // 16*128*128*64 total
  int co = tid & 63;
  int t = tid >> 6;
  int ow = t & 127; t >>= 7;
  int oh = t & 127;
  int b = t >> 7;
  int fl = *flag;
  float acc = bf_[co];
  int ih0 = oh * 2 - 1, iw0 = ow * 2 - 1;
  for (int ci = 0; ci < 3; ++ci) {
    const float* wp = wf + (co * 3 + ci) * 16;
    long pbase = ((long)(b * 3 + ci)) * 65536;
    #pragma unroll
    for (int kh = 0; kh < 4; ++kh) {
      int ih = ih0 + kh;
      if ((unsigned)ih >= 256u) continue;
      long rbase = pbase + (long)ih * 256;
      #pragma unroll
      for (int kw = 0; kw < 4; ++kw) {
        int iw = iw0 + kw;
        if ((unsigned)iw < 256u)
          acc = fmaf(ld_any(x, rbase + iw, fl), wp[kh * 4 + kw], acc);
      }
    }
  }
  act1p[((long)(b * 130 + oh + 1) * 130 + ow + 1) * 64 + co] =
      __float2bfloat16(fmaxf(acc, 0.f));
}

// ------------------------------------------- MFMA implicit-GEMM tap conv
// NHWC bf16 in (zero-padded), bf16 out, bias+relu fused.
// S=2: taps t: dy=t>>2, dx=t&3 (ihp = 2*oh + kh).  S=1 (convT class pq):
// taps t: dy = p-(t>>1)+1, dx = q-(t&1)+1.  Block: 4 waves = 2(M)x2(N),
// wave tile M32 x N64; block tile M64 x N128 (TR rows x TC cols).
template <int COUT, int CINT, int TC, int S, int NT, int INC>
__global__ __launch_bounds__(256) void mfma_conv(
    const bf16* __restrict__ in1, const bf16* __restrict__ in2,
    long inImgS, int inRowS,
    const bf16* __restrict__ w, const float* __restrict__ bias,
    bf16* __restrict__ outp, long outImgS, int oRS, int oCS, int pq) {
  constexpr int TR = 128 / TC;
  constexpr int KC = CINT / 32;
  constexpr int KSPLIT = (CINT > INC) ? (INC / 32) : KC;
  const int lane = threadIdx.x & 63;
  const int wv = threadIdx.x >> 6;
  const int wm = wv & 1, wn = wv >> 1;
  const int ln = lane & 15, quad = lane >> 4;
  const int mTile = blockIdx.y * 64;
  const int oh0 = blockIdx.x * TR;
  const int b = blockIdx.z;
  const int p = pq >> 1, q = pq & 1;

  long posOff[4];
  int rr[4], cc[4];
  #pragma unroll
  for (int bf = 0; bf < 4; ++bf) {
    int n = wn * 64 + bf * 16 + ln;
    int r = n / TC, c = n % TC;
    rr[bf] = r; cc[bf] = c;
    posOff[bf] = (long)(S * (oh0 + r)) * inRowS + (long)(S * c) * INC;
  }
  const bf16* inb1 = in1 + (long)b * inImgS;
  const bf16* inb2 = in2 + (long)b * inImgS;

  float4v acc[2][4];
  #pragma unroll
  for (int i = 0; i < 2; ++i)
    #pragma unroll
    for (int j = 0; j < 4; ++j) acc[i][j] = {0.f, 0.f, 0.f, 0.f};

  for (int t = 0; t < NT; ++t) {
    int dy, dx;
    if (S == 2) { dy = t >> 2; dx = t & 3; }
    else        { dy = p - (t >> 1) + 1; dx = q - (t & 1) + 1; }
    const long tapOff = (long)dy * inRowS + (long)dx * INC;
    const bf16* wt = w + (long)t * COUT * CINT;
    const bf16* wk0 = wt + (long)(mTile + wm * 32 + ln) * CINT + quad * 8;
    #pragma unroll
    for (int kc = 0; kc < KC; ++kc) {
      short8 a0 = *(const short8*)(wk0 + kc * 32);
      short8 a1 = *(const short8*)(wk0 + kc * 32 + 16 * CINT);
      const bf16* bp = (kc < KSPLIT) ? inb1 : inb2;
      int kOff = (kc < KSPLIT ? kc : kc - KSPLIT) * 32 + quad * 8;
      #pragma unroll
      for (int bf = 0; bf < 4; ++bf) {
        short8 bv = *(const short8*)(bp + posOff[bf] + tapOff + kOff);
        acc[0][bf] = __builtin_amdgcn_mfma_f32_16x16x32_bf16(a0, bv, acc[0][bf], 0, 0, 0);
        acc[1][bf] = __builtin_amdgcn_mfma_f32_16x16x32_bf16(a1, bv, acc[1][bf], 0, 0, 0);
      }
    }
  }

  bf16* outb = outp + (long)b * outImgS;
  #pragma unroll
  for (int mf = 0; mf < 2; ++mf) {
    int coB = mTile + wm * 32 + mf * 16 + quad * 4;
    float4v bv4 = *(const float4v*)(bias + coB);
    #pragma unroll
    for (int bf = 0; bf < 4; ++bf) {
      float4v v = acc[mf][bf];
      ushort4v o;
      #pragma unroll
      for (int e = 0; e < 4; ++e)
        o[e] = f2bfbits(fmaxf(v[e] + bv4[e], 0.f));
      long oaddr = (long)(oh0 + rr[bf]) * oRS + (long)cc[bf] * oCS + coB;
      *(ushort4v*)(outb + oaddr) = o;
    }
  }
}

// ------------------------------------------------------------- VQ quantize
__global__ __launch_bounds__(256) void vq_nhwc(
    const bf16* __restrict__ z, long zImgS, int zRowS,
    const bf16* __restrict__ emb, const float* __restrict__ embsq,
    bf16* __restrict__ zq, long qImgS, int qRowS,
    float* __restrict__ loss_acc, int HW, int Wv) {
  __shared__ float se[64 * 128];
  __shared__ float ssq[64];
  const int n = blockIdx.x * 256 + threadIdx.x;
  const int b = n / HW, rem = n % HW;
  const int y = rem / Wv, xx = rem % Wv;
  const bf16* zrow = z + (long)b * zImgS + (long)y * zRowS + (long)xx * 128;
  float zp[128];
  {
    const uint4* zr4 = (const uint4*)zrow;
    #pragma unroll
    for (int j = 0; j < 16; ++j) unpack_u4(zr4[j], zp + j * 8);
  }
  float best = 3.4e38f; int bestk = 0;
  for (int k0 = 0; k0 < 512; k0 += 64) {
    __syncthreads();
    #pragma unroll
    for (int tt = 0; tt < 32; ++tt) {
      int idx = tt * 256 + threadIdx.x;
      se[idx] = b2f(emb[(long)k0 * 128 + idx]);
    }
    if (threadIdx.x < 64) ssq[threadIdx.x] = embsq[k0 + threadIdx.x];
    __syncthreads();
    for (int kk = 0; kk < 64; kk += 4) {
      float d0 = 0.f, d1 = 0.f, d2 = 0.f, d3 = 0.f;
      const float* e0 = se + kk * 128;
      #pragma unroll
      for (int c = 0; c < 128; ++c) {
        float zc = zp[c];
        d0 = fmaf(zc, e0[c], d0);
        d1 = fmaf(zc, e0[128 + c], d1);
        d2 = fmaf(zc, e0[256 + c], d2);
        d3 = fmaf(zc, e0[384 + c], d3);
      }
      float s0 = fmaf(-2.f, d0, ssq[kk + 0]);
      float s1 = fmaf(-2.f, d1, ssq[kk + 1]);
      float s2 = fmaf(-2.f, d2, ssq[kk + 2]);
      float s3 = fmaf(-2.f, d3, ssq[kk + 3]);
      if (s0 < best) { best = s0; bestk = k0 + kk + 0; }
      if (s1 < best) { best = s1; bestk = k0 + kk + 1; }
      if (s2 < best) { best = s2; bestk = k0 + kk + 2; }
      if (s3 < best) { best = s3; bestk = k0 + kk + 3; }
    }
  }
  const uint4* er = (const uint4*)(emb + (long)bestk * 128);
  uint4* qrow = (uint4*)(zq + (long)b * qImgS + (long)y * qRowS + (long)xx * 128);
  float lsum = 0.f;
  #pragma unroll
  for (int j = 0; j < 16; ++j) {
    uint4 u = er[j];
    qrow[j] = u;
    float ev[8];
    unpack_u4(u, ev);
    #pragma unroll
    for (int e = 0; e < 8; ++e) {
      float dv = ev[e] - zp[j * 8 + e];
      lsum = fmaf(dv, dv, lsum);
    }
  }
  for (int o = 32; o > 0; o >>= 1) lsum += __shfl_down(lsum, o, 64);
  if ((threadIdx.x & 63) == 0) atomicAdd(loss_acc, lsum);
}

// ----------------------------------------- final convT(64->3) + sigmoid
__global__ __launch_bounds__(256) void final_convt_sig(
    const bf16* __restrict__ hp, const float* __restrict__ wf,
    const float* __restrict__ bf_, float* __restrict__ out) {
  int tid = blockIdx.x * 256 + threadIdx.x;   // 16*256*256
  int ow = tid & 255; int t = tid >> 8;
  int oh = t & 255; int b = t >> 8;
  int p = oh & 1, y = oh >> 1, q = ow & 1, xx = ow >> 1;
  float a0 = bf_[0], a1 = bf_[1], a2 = bf_[2];
  const bf16* hb = hp + (long)b * 1081600;
  #pragma unroll
  for (int s = 0; s < 2; ++s) {
    #pragma unroll
    for (int t2 = 0; t2 < 2; ++t2) {
      int khkw = (2 * s + 1 - p) * 4 + (2 * t2 + 1 - q);
      const uint4* r4 = (const uint4*)(hb + (long)(y + p - s + 1) * 8320 +
                                       (long)(xx + q - t2 + 1) * 64);
      #pragma unroll
      for (int j = 0; j < 8; ++j) {
        float v[8];
        unpack_u4(r4[j], v);
        #pragma unroll
        for (int e = 0; e < 8; ++e) {
          const float* wc = wf + (j * 8 + e) * 48 + khkw;
          a0 = fmaf(v[e], wc[0], a0);
          a1 = fmaf(v[e], wc[16], a1);
          a2 = fmaf(v[e], wc[32], a2);
        }
      }
    }
  }
  long ob = (long)b * 196608 + (long)oh * 256 + ow;
  out[ob]          = 1.f / (1.f + expf(-a0));
  out[ob + 65536]  = 1.f / (1.f + expf(-a1));
  out[ob + 131072] = 1.f / (1.f + expf(-a2));
}

__global__ void finalize_loss_kernel(const float* __restrict__ lacc, float* __restrict__ out) {
  if (threadIdx.x == 0) {
    float lt = lacc[0] * (1.5f / 2097152.f);
    float lb = lacc[1] * (1.5f / 8388608.f);
    *out = lt + lb;
  }
}

// ------------------------------------------------------------------ launch
extern "C" void kernel_launch(void* const* d_in, const int* in_sizes, int n_in,
                              void* d_out, int out_size, void* d_ws, size_t ws_size,
                              hipStream_t stream) {
  float* out = (float*)d_out;
  char* base = (char*)d_ws;
  size_t off = 0;
  auto alloc = [&](size_t bytes) {
    void* pp = base + off;
    off = (off + bytes + 255) & ~(size_t)255;
    return pp;
  };

  int* flag = (int*)alloc(256);
  // fp32 small buffers
  float* wB1f  = (float*)alloc(3072 * 4);
  float* beB1f = (float*)alloc(64 * 4);
  float* beB2f = (float*)alloc(128 * 4);
  float* beTf  = (float*)alloc(128 * 4);
  float* bdTf  = (float*)alloc(128 * 4);
  float* bd1f  = (float*)alloc(64 * 4);
  float* wd2f  = (float*)alloc(3072 * 4);
  float* bd2f  = (float*)alloc(3 * 4);
  float* sqT   = (float*)alloc(512 * 4);
  float* sqB   = (float*)alloc(512 * 4);
  float* lacc  = (float*)alloc(2 * 4);
  // bf16 repacked weights / embeddings
  bf16* Wt2  = (bf16*)alloc((size_t)131072 * 2);  // [16][128][64]
  bf16* Wtt  = (bf16*)alloc((size_t)262144 * 2);  // [16][128][128]
  bf16* Wdt  = (bf16*)alloc((size_t)262144 * 2);  // [4][4][128][128]
  bf16* Wd1  = (bf16*)alloc((size_t)262144 * 2);  // [4][4][64][256]
  bf16* embT = (bf16*)alloc((size_t)65536 * 2);
  bf16* embB = (bf16*)alloc((size_t)65536 * 2);
  // padded NHWC activations (contiguous; zeroed each call)
  bf16* act1p = (bf16*)alloc((size_t)17305600 * 2);  // [16][130][130][64]
  bf16* zbp   = (bf16*)alloc((size_t)8921088 * 2);   // [16][66][66][128]
  bf16* zqtp  = (bf16*)alloc((size_t)2367488 * 2);   // [16][34][34][128]
  bf16* eup   = (bf16*)alloc((size_t)8921088 * 2);   // [16][66][66][128]
  bf16* fqp   = (bf16*)alloc((size_t)8921088 * 2);   // [16][66][66][128]
  bf16* hp    = (bf16*)alloc((size_t)17305600 * 2);  // [16][130][130][64]
  bf16* ztp   = (bf16*)alloc((size_t)2097152 * 2);   // [16][32][32][128]

  const long actBytes = ((char*)(ztp + 2097152)) - ((char*)act1p);
  const long n4 = actBytes / 16;

  detect_dtype_kernel<<<1, 256, 0, stream>>>(d_in[0], flag);
  zero_kernel<<<4096, 256, 0, stream>>>((uint4*)act1p, n4);
  zero2_kernel<<<1, 64, 0, stream>>>(lacc);

  // converts / repacks
  conv_f32<<<12, 256, 0, stream>>>(d_in[1], wB1f, 3072, flag);
  conv_f32<<<1, 256, 0, stream>>>(d_in[2], beB1f, 64, flag);
  conv_f32<<<1, 256, 0, stream>>>(d_in[4], beB2f, 128, flag);
  conv_f32<<<1, 256, 0, stream>>>(d_in[6], beTf, 128, flag);
  conv_f32<<<1, 256, 0, stream>>>(d_in[10], bdTf, 128, flag);
  conv_f32<<<1, 256, 0, stream>>>(d_in[12], bd1f, 64, flag);
  conv_f32<<<12, 256, 0, stream>>>(d_in[13], wd2f, 3072, flag);
  conv_f32<<<1, 256, 0, stream>>>(d_in[14], bd2f, 3, flag);
  conv_bf16<<<256, 256, 0, stream>>>(d_in[7], embT, 65536, flag);
  conv_bf16<<<256, 256, 0, stream>>>(d_in[8], embB, 65536, flag);
  embsq_kernel<<<2, 256, 0, stream>>>(embT, sqT);
  embsq_kernel<<<2, 256, 0, stream>>>(embB, sqB);
  rp_conv_w<128, 64><<<512, 256, 0, stream>>>(d_in[3], Wt2, flag);
  rp_conv_w<128, 128><<<1024, 256, 0, stream>>>(d_in[5], Wtt, flag);
  rp_convt_w<128, 128><<<1024, 256, 0, stream>>>(d_in[9], Wdt, flag);
  rp_convt_w<256, 64><<<1024, 256, 0, stream>>>(d_in[11], Wd1, flag);

  // encoder
  conv1_nhwc<<<65536, 256, 0, stream>>>(d_in[0], flag, wB1f, beB1f, act1p);
  mfma_conv<128, 64, 64, 2, 16, 64><<<dim3(32, 2, 16), 256, 0, stream>>>(
      act1p, act1p, 1081600, 8320, Wt2, beB2f, zbp + 8576, 557568, 8448, 128, 0);
  mfma_conv<128, 128, 32, 2, 16, 128><<<dim3(8, 2, 16), 256, 0, stream>>>(
      zbp, zbp, 557568, 8448, Wtt, beTf, ztp, 131072, 4096, 128, 0);

  // VQ top: z_top [16,32,32,128] -> zq into padded zqtp
  vq_nhwc<<<64, 256, 0, stream>>>(ztp, 131072, 4096, embT, sqT,
                                  zqtp + 4480, 147968, 4352, lacc + 0, 1024, 32);

  // decoder_top upsample: 4 parity classes
  for (int cls = 0; cls < 4; ++cls) {
    int p = cls >> 1, q = cls & 1;
    mfma_conv<128, 128, 32, 1, 4, 128><<<dim3(8, 2, 16), 256, 0, stream>>>(
        zqtp, zqtp, 147968, 4352, Wdt + (long)cls * 65536, bdTf,
        eup + (long)(p + 1) * 8448 + (q + 1) * 128, 557568, 16896, 256, cls);
  }

  // VQ bottom
  vq_nhwc<<<256, 256, 0, stream>>>(zbp + 8576, 557568, 8448, embB, sqB,
                                   fqp + 8576, 557568, 8448, lacc + 1, 4096, 64);

  // decoder conv: concat(Fq, Eu) -> h (4 parity classes)
  for (int cls = 0; cls < 4; ++cls) {
    int p = cls >> 1, q = cls & 1;
    mfma_conv<64, 256, 64, 1, 4, 128><<<dim3(32, 1, 16), 256, 0, stream>>>(
        fqp, eup, 557568, 8448, Wd1 + (long)cls * 65536, bd1f,
        hp + (long)(p + 1) * 8320 + (q + 1) * 64, 1081600, 16640, 128, cls);
  }

  // final convT + sigmoid -> fp32 NCHW output
  final_convt_sig<<<4096, 256, 0, stream>>>(hp, wd2f, bd2f, out);
  finalize_loss_kernel<<<1, 64, 0, stream>>>(lacc, out + 3145728);
}